// Round 1
// 329.928 us; speedup vs baseline: 1.0956x; 1.0956x over previous
//
#include <hip/hip_runtime.h>
#include <stdint.h>

typedef __attribute__((ext_vector_type(4))) float f32x4;
typedef __attribute__((ext_vector_type(16))) float f32x16;
typedef __attribute__((ext_vector_type(8))) __bf16 bf16x8;
typedef unsigned short u16;

#define AS1 __attribute__((address_space(1)))
#define AS3 __attribute__((address_space(3)))

__device__ __forceinline__ u16 f2bf(float f) {
  uint32_t u = __float_as_uint(f);
  u += 0x7fffu + ((u >> 16) & 1u);
  return (u16)(u >> 16);
}
__device__ __forceinline__ float bf2f(u16 s) {
  return __uint_as_float(((uint32_t)s) << 16);
}

__device__ __forceinline__ void gload_lds16(const void* g, void* l) {
  __builtin_amdgcn_global_load_lds((const AS1 void*)g, (AS3 void*)l, 16, 0, 0);
}

// ---------------------------------------------------------------------------
// Kernel 0: f32 -> bf16 convert (x, w) + zero-init of ctxraw/colsum, one dispatch.
// [unchanged]
// ---------------------------------------------------------------------------
__global__ __launch_bounds__(256) void cvt_all(const float* __restrict__ X,
                                               const float* __restrict__ W,
                                               u16* __restrict__ x16,
                                               u16* __restrict__ w16,
                                               float* __restrict__ ctxbase) {
  const int gb = blockIdx.x;
  if (gb >= 9728) {  // zero ctxraw (64*64*64) + colsum (64*64) = 66560 f32x4
    const int idx = (gb - 9728) * 256 + threadIdx.x;
    for (int i = idx; i < 66560; i += 1024)
      ((f32x4*)ctxbase)[i] = (f32x4){0.f, 0.f, 0.f, 0.f};
    return;
  }
  const float* src;
  u16* dst;
  int i;
  if (gb < 8192) {
    src = X; dst = x16; i = gb * 256 + threadIdx.x;
  } else {
    src = W; dst = w16; i = (gb - 8192) * 256 + threadIdx.x;
  }
  const f32x4 a = ((const f32x4*)src)[2 * i];
  const f32x4 b = ((const f32x4*)src)[2 * i + 1];
  ushort4 lo, hi;
  lo.x = f2bf(a.x); lo.y = f2bf(a.y); lo.z = f2bf(a.z); lo.w = f2bf(a.w);
  hi.x = f2bf(b.x); hi.y = f2bf(b.y); hi.z = f2bf(b.z); hi.w = f2bf(b.w);
  ((ushort4*)dst)[2 * i] = lo;
  ((ushort4*)dst)[2 * i + 1] = hi;
}

// ---------------------------------------------------------------------------
// Kernel 1 v3: qkv = x @ w^T  (M=16384, K=1024, O=3072), bf16 in.
// 256x256 tile, BK=64, 512 thr = 8 waves (2M x 4N), each wave 128x64 out via
// mfma_f32_16x16x32_bf16 (acc[8][4] f32x4 = 128 VGPR).
// 8-phase schedule (T2+T3+T4+T5): LDS = ring of 8 x 16KB units
//   unit = {A-low, A-high, B-low, B-high} x parity.  A-low = tile rows
//   {0-63,128-191} (the rows quadrants Q0/Q1 read), A-high the rest; B-low =
//   o-cols {wn+0..31} for each wave (read by Q0/Q3), B-high the rest.
// Per K-tile (BK=64): 4 phases = 4 C-quadrants x 16 MFMA.  Each phase:
//   ds_reads (4-12 b128) ; stage ONE unit via global_load_lds (2/thread) ;
//   s_barrier ; lgkmcnt(0) ; setprio(1) ; 16 MFMA ; setprio(0) ; s_barrier.
// Stage schedule (WAR-safe: each unit overwritten 1 phase after last read):
//   p0: AH(t+1)  p1: BL(t+1)  p2: AL(t+2)  p3: BH(t+2)
// Counted vmcnt(4) once per tile at p3-end (2 units = 4 loads stay in flight
// across barriers; never drain to 0 mid-loop -> T4).  vmcnt(0) only at t=14.
// XOR chunk swizzle folded into GLOBAL fetch address (linear LDS dest,
// inverse-swizzled source, swizzled ds_read) -- rule #21.  XCD-aware remap
// (768 % 8 == 0 so the simple bijective form is valid).
// ---------------------------------------------------------------------------
__global__ __launch_bounds__(512, 2) void qkv_gemm(const u16* __restrict__ X,
                                                   const u16* __restrict__ W,
                                                   float* __restrict__ QOUT,
                                                   u16* __restrict__ KV) {
  __shared__ __attribute__((aligned(16))) u16 lds[8 * 128 * 64];  // 128 KiB

  const int t = threadIdx.x;
  // XCD-aware block remap (perf heuristic only; bijective since 768%8==0)
  const int D = blockIdx.x;
  const int xcd = D & 7;
  const int s = D >> 3;                 // 0..95 sequential per XCD
  const int otile = s % 12;             // o fastest: X panel stays hot in L2
  const int mtile = (s / 12) * 8 + xcd; // 0..63
  const int oblk = otile << 8;
  const int mblk = mtile << 8;

  const int wv = t >> 6;
  const int l = t & 63;
  const int wm = wv >> 2;   // 0..1 : wave row (128 rows each)
  const int wnx = wv & 3;   // 0..3 : wave col (64 cols each)
  const int l15 = l & 15;
  const int sp = t & 7;

  char* ldsc = (char*)lds;

  // --- staging: unit u = (par*4 + type), type 0=AL 1=AH 2=BL 3=BH ----------
  auto stageA = [&](int tau, int h, int par) {
#pragma unroll
    for (int j = 0; j < 2; j++) {
      const int ur = (j << 6) | (t >> 3);
      const int R = ((ur >> 6) << 7) | (h << 6) | (ur & 63);
      const u16* g = X + (size_t)(mblk + R) * 1024 + (tau << 6) +
                     ((sp ^ (ur & 7)) << 3);
      gload_lds16(g, ldsc + (((par << 2) | h) << 14) + (((j << 9) | t) << 4));
    }
  };
  auto stageB = [&](int tau, int h, int par) {
#pragma unroll
    for (int j = 0; j < 2; j++) {
      const int ur = (j << 6) | (t >> 3);
      const int R = ((ur >> 5) << 6) | (h << 5) | (ur & 31);
      const u16* g = W + (size_t)(oblk + R) * 1024 + (tau << 6) +
                     ((sp ^ (ur & 7)) << 3);
      gload_lds16(g,
                  ldsc + (((par << 2) | 2 | h) << 14) + (((j << 9) | t) << 4));
    }
  };

  // --- fragment reads (ds_read_b128, swizzled chunk = c ^ (l&7)) -----------
  const int co0 = (((l >> 4) ^ (l & 7)) << 4);
  const int co1 = ((((l >> 4) | 4) ^ (l & 7)) << 4);
  const int aOff = ((wm << 6) | l15) << 7;   // unit-row * 128B
  const int bOff = ((wnx << 5) | l15) << 7;

  bf16x8 af[2][4], bfr[2][2];
  auto loadA = [&](int h, int par) {
    const char* base = ldsc + (((par << 2) | h) << 14) + aOff;
#pragma unroll
    for (int fm = 0; fm < 4; fm++) {
      af[0][fm] = *(const bf16x8*)(base + (fm << 11) + co0);
      af[1][fm] = *(const bf16x8*)(base + (fm << 11) + co1);
    }
  };
  auto loadB = [&](int nh, int par) {
    const char* base = ldsc + (((par << 2) | 2 | nh) << 14) + bOff;
#pragma unroll
    for (int fn = 0; fn < 2; fn++) {
      bfr[0][fn] = *(const bf16x8*)(base + (fn << 11) + co0);
      bfr[1][fn] = *(const bf16x8*)(base + (fn << 11) + co1);
    }
  };

  f32x4 acc[8][4];
#pragma unroll
  for (int i = 0; i < 8; i++)
#pragma unroll
    for (int j = 0; j < 4; j++) acc[i][j] = (f32x4){0.f, 0.f, 0.f, 0.f};

  auto mfma16 = [&](int ah, int nh) {
#pragma unroll
    for (int fm = 0; fm < 4; fm++)
#pragma unroll
      for (int fn = 0; fn < 2; fn++)
#pragma unroll
        for (int ks = 0; ks < 2; ks++)
          acc[(ah << 2) | fm][(nh << 1) | fn] =
              __builtin_amdgcn_mfma_f32_16x16x32_bf16(
                  af[ks][fm], bfr[ks][fn], acc[(ah << 2) | fm][(nh << 1) | fn],
                  0, 0, 0);
  };

  // --- prologue: 6 units; vmcnt(4) leaves AL1,BH1 in flight ----------------
  stageA(0, 0, 0);  // AL0
  stageA(0, 1, 0);  // AH0
  stageB(0, 0, 0);  // BL0
  stageB(0, 1, 0);  // BH0
  stageA(1, 0, 1);  // AL1
  stageB(1, 1, 1);  // BH1
  asm volatile("s_waitcnt vmcnt(4)" ::: "memory");
  __builtin_amdgcn_s_barrier();

#pragma unroll 1
  for (int tau = 0; tau < 16; tau++) {
    const int par = tau & 1;
    // phase 0: Q0 = (A-low, B-low)
    loadA(0, par);
    loadB(0, par);
    if (tau < 15) stageA(tau + 1, 1, par ^ 1);  // AH(t+1)
    __builtin_amdgcn_s_barrier();
    asm volatile("s_waitcnt lgkmcnt(0)" ::: "memory");
    __builtin_amdgcn_s_setprio(1);
    mfma16(0, 0);
    __builtin_amdgcn_s_setprio(0);
    __builtin_amdgcn_s_barrier();
    // phase 1: Q1 = (A-low, B-high)   (af reused)
    loadB(1, par);
    if (tau < 15) stageB(tau + 1, 0, par ^ 1);  // BL(t+1)
    __builtin_amdgcn_s_barrier();
    asm volatile("s_waitcnt lgkmcnt(0)" ::: "memory");
    __builtin_amdgcn_s_setprio(1);
    mfma16(0, 1);
    __builtin_amdgcn_s_setprio(0);
    __builtin_amdgcn_s_barrier();
    // phase 2: Q2 = (A-high, B-high)  (bfr reused)
    loadA(1, par);
    if (tau < 14) stageA(tau + 2, 0, par);  // AL(t+2): AL(t) last read p0
    __builtin_amdgcn_s_barrier();
    asm volatile("s_waitcnt lgkmcnt(0)" ::: "memory");
    __builtin_amdgcn_s_setprio(1);
    mfma16(1, 1);
    __builtin_amdgcn_s_setprio(0);
    __builtin_amdgcn_s_barrier();
    // phase 3: Q3 = (A-high, B-low)
    loadB(0, par);
    if (tau < 14) stageB(tau + 2, 1, par);  // BH(t+2): BH(t) last read p1
    __builtin_amdgcn_s_barrier();
    asm volatile("s_waitcnt lgkmcnt(0)" ::: "memory");
    __builtin_amdgcn_s_setprio(1);
    mfma16(1, 0);
    __builtin_amdgcn_s_setprio(0);
    // tile-boundary counted wait: all units of tile t+1 retired, keep the
    // 2 newest (AL(t+2), BH(t+2)) in flight.  Only the last boundary drains.
    if (tau < 14) {
      asm volatile("s_waitcnt vmcnt(4)" ::: "memory");
    } else if (tau == 14) {
      asm volatile("s_waitcnt vmcnt(0)" ::: "memory");
    }
    __builtin_amdgcn_s_barrier();
  }

  // --- epilogue: C/D 16x16 layout col=lane&15, row=(lane>>4)*4+reg ---------
  const bool is_q = (oblk < 1024);
  const int rbase = mblk + (wm << 7) + ((l >> 4) << 2);
  const int cbase = oblk + (wnx << 6) + l15;
#pragma unroll
  for (int fm = 0; fm < 8; fm++) {
#pragma unroll
    for (int fn = 0; fn < 4; fn++) {
      const int colg = cbase + (fn << 4);
#pragma unroll
      for (int r = 0; r < 4; r++) {
        const int rowg = rbase + (fm << 4) + r;
        if (is_q) {
          const int b = rowg >> 12, n = rowg & 4095;
          const int h = colg >> 6, d = colg & 63;
          QOUT[(((size_t)((b << 4) + h) << 12) + n) * 64 + d] = acc[fm][fn][r];
        } else {
          KV[(size_t)rowg * 2048 + (colg - 1024)] = f2bf(acc[fm][fn][r]);
        }
      }
    }
  }
}

// ---------------------------------------------------------------------------
// Kernel 2: ctxraw[bh][d][e] += sum_n exp(k[n,d]) * v[n,e]; colsum likewise.
// [unchanged]
// ---------------------------------------------------------------------------
__global__ __launch_bounds__(256) void ctx_colsum(const u16* __restrict__ KV,
                                                  float* __restrict__ ctxraw,
                                                  float* __restrict__ colsum) {
  __shared__ __attribute__((aligned(16))) float ek[16 * 64];
  __shared__ __attribute__((aligned(16))) float ev[16 * 64];

  const int t = threadIdx.x;
  const int bh = blockIdx.y;
  const int b = bh >> 4, h = bh & 15;
  const u16* kb = KV + ((size_t)b << 12) * 2048 + (h << 6);
  const int tr = t >> 4, tc = t & 15;
  const int srow = t >> 4;
  const int sq = t & 15;

  float acc[4][4] = {};
  float rs[4] = {0.f, 0.f, 0.f, 0.f};

  const int n0b = blockIdx.x << 8;

  uint2 pk, pv;
  {
    const size_t roff = (size_t)(n0b + srow) * 2048 + (sq << 2);
    pk = *(const uint2*)(kb + roff);
    pv = *(const uint2*)(kb + roff + 1024);
  }

  for (int c = 0; c < 16; c++) {
    {
      f32x4 ke, vv;
      ke.x = __expf(bf2f((u16)(pk.x & 0xffff)));
      ke.y = __expf(bf2f((u16)(pk.x >> 16)));
      ke.z = __expf(bf2f((u16)(pk.y & 0xffff)));
      ke.w = __expf(bf2f((u16)(pk.y >> 16)));
      vv.x = bf2f((u16)(pv.x & 0xffff));
      vv.y = bf2f((u16)(pv.x >> 16));
      vv.z = bf2f((u16)(pv.y & 0xffff));
      vv.w = bf2f((u16)(pv.y >> 16));
      const int p = (sq ^ srow) & 15;
      *(f32x4*)&ek[(srow << 6) + (p << 2)] = ke;
      *(f32x4*)&ev[(srow << 6) + (p << 2)] = vv;
    }
    __syncthreads();
    if (c + 1 < 16) {
      const size_t roff = (size_t)(n0b + ((c + 1) << 4) + srow) * 2048 + (sq << 2);
      pk = *(const uint2*)(kb + roff);
      pv = *(const uint2*)(kb + roff + 1024);
    }
#pragma unroll
    for (int nl = 0; nl < 16; nl++) {
      const f32x4 ka = *(const f32x4*)&ek[(nl << 6) + (((tr ^ nl) & 15) << 2)];
      const f32x4 vb = *(const f32x4*)&ev[(nl << 6) + (((tc ^ nl) & 15) << 2)];
      rs[0] += ka.x; rs[1] += ka.y; rs[2] += ka.z; rs[3] += ka.w;
#pragma unroll
      for (int a = 0; a < 4; a++) {
        acc[a][0] += ka[a] * vb.x;
        acc[a][1] += ka[a] * vb.y;
        acc[a][2] += ka[a] * vb.z;
        acc[a][3] += ka[a] * vb.w;
      }
    }
    __syncthreads();
  }

  float* dst = ctxraw + ((size_t)bh << 12);
#pragma unroll
  for (int a = 0; a < 4; a++)
#pragma unroll
    for (int e = 0; e < 4; e++)
      atomicAdd(&dst[((tr << 2) + a) * 64 + (tc << 2) + e], acc[a][e]);
  if (tc == 0) {
#pragma unroll
    for (int a = 0; a < 4; a++) atomicAdd(&colsum[(bh << 6) + (tr << 2) + a], rs[a]);
  }
}

// ---------------------------------------------------------------------------
// Kernel 3: out[bh,n,e] = (0.125/rowsum_n) * sum_d exp(q[n,d]) * ctx'[d,e]
// [unchanged]  Q staged as f32 in d_out [b,h,n,d], overwritten in-place.
// ---------------------------------------------------------------------------
__global__ __launch_bounds__(256) void out_kernel(const float* __restrict__ ctxraw,
                                                  const float* __restrict__ colsum,
                                                  float* __restrict__ OUT) {
  __shared__ __attribute__((aligned(16))) float ctxs[64 * 64];
  __shared__ __attribute__((aligned(16))) float qt[64 * 64];

  const int t = threadIdx.x;
  const int bh = blockIdx.y;
  const float* craw = ctxraw + ((size_t)bh << 12);
  const float* csum = colsum + (bh << 6);

#pragma unroll
  for (int j = 0; j < 16; j++) {
    const int idx = (j << 8) + t;
    ctxs[idx] = craw[idx] / csum[idx >> 6];
  }

  const int n0 = blockIdx.x << 6;
  float* qbase = OUT + (((size_t)bh << 12) + n0) * 64;
  {
#pragma unroll
    for (int p = 0; p < 4; p++) {
      const int c = (p << 8) + t;
      const int nl = c >> 4;
      const int dg = c & 15;
      const f32x4 qv = *(const f32x4*)(qbase + nl * 64 + (dg << 2));
      const int swz = ((nl >> 2) ^ dg) << 2;
#pragma unroll
      for (int e = 0; e < 4; e++) {
        const int d = (dg << 2) + e;
        qt[(d << 6) + swz + (nl & 3)] = __expf(qv[e]);
      }
    }
  }
  __syncthreads();

  const int tr = t >> 4, tc = t & 15;
  float acc[4][4] = {};
  f32x4 rsv = {0.f, 0.f, 0.f, 0.f};
#pragma unroll 4
  for (int d = 0; d < 64; d++) {
    const f32x4 qa = *(const f32x4*)&qt[(d << 6) + ((tr ^ (d >> 2)) << 2)];
    const f32x4 cb = *(const f32x4*)&ctxs[(d << 6) + (tc << 2)];
    rsv += qa;
#pragma unroll
    for (int a = 0; a < 4; a++) {
      acc[a][0] += qa[a] * cb.x;
      acc[a][1] += qa[a] * cb.y;
      acc[a][2] += qa[a] * cb.z;
      acc[a][3] += qa[a] * cb.w;
    }
  }
  __syncthreads();

#pragma unroll
  for (int a = 0; a < 4; a++) {
    const float inv = 0.125f / rsv[a];
    const int row = (tr << 2) + a;
    f32x4 pk;
    pk.x = acc[a][0] * inv;
    pk.y = acc[a][1] * inv;
    pk.z = acc[a][2] * inv;
    pk.w = acc[a][3] * inv;
    *(f32x4*)(qbase + row * 64 + (tc << 2)) = pk;
  }
}

extern "C" void kernel_launch(void* const* d_in, const int* in_sizes, int n_in,
                              void* d_out, int out_size, void* d_ws, size_t ws_size,
                              hipStream_t stream) {
  const float* Xf = (const float*)d_in[0];
  const float* Wf = (const float*)d_in[1];

  u16* x16 = (u16*)d_ws;
  u16* w16 = x16 + (size_t)16384 * 1024;
  u16* KV = w16 + (size_t)3072 * 1024;
  float* ctxraw = (float*)(KV + (size_t)16384 * 2048);
  float* colsum = ctxraw + 64 * 64 * 64;
  float* QOUT = (float*)d_out;

  cvt_all<<<dim3(9732), 256, 0, stream>>>(Xf, Wf, x16, w16, ctxraw);
  qkv_gemm<<<dim3(768), 512, 0, stream>>>(x16, w16, QOUT, KV);
  ctx_colsum<<<dim3(16, 64), 256, 0, stream>>>(KV, ctxraw, colsum);
  out_kernel<<<dim3(64, 64), 256, 0, stream>>>(ctxraw, colsum, QOUT);
}

// Round 3
// 324.883 us; speedup vs baseline: 1.1126x; 1.0155x over previous
//
#include <hip/hip_runtime.h>
#include <stdint.h>

typedef __attribute__((ext_vector_type(4))) float f32x4;
typedef __attribute__((ext_vector_type(16))) float f32x16;
typedef __attribute__((ext_vector_type(8))) __bf16 bf16x8;
typedef unsigned short u16;

#define AS1 __attribute__((address_space(1)))
#define AS3 __attribute__((address_space(3)))

__device__ __forceinline__ u16 f2bf(float f) {
  uint32_t u = __float_as_uint(f);
  u += 0x7fffu + ((u >> 16) & 1u);
  return (u16)(u >> 16);
}
__device__ __forceinline__ float bf2f(u16 s) {
  return __uint_as_float(((uint32_t)s) << 16);
}

__device__ __forceinline__ void gload_lds16(const void* g, void* l) {
  __builtin_amdgcn_global_load_lds((const AS1 void*)g, (AS3 void*)l, 16, 0, 0);
}

// ---------------------------------------------------------------------------
// Kernel 0: f32 -> bf16 convert (x, w) + zero-init of ctxraw/colsum. [unchanged]
// ---------------------------------------------------------------------------
__global__ __launch_bounds__(256) void cvt_all(const float* __restrict__ X,
                                               const float* __restrict__ W,
                                               u16* __restrict__ x16,
                                               u16* __restrict__ w16,
                                               float* __restrict__ ctxbase) {
  const int gb = blockIdx.x;
  if (gb >= 9728) {
    const int idx = (gb - 9728) * 256 + threadIdx.x;
    for (int i = idx; i < 66560; i += 1024)
      ((f32x4*)ctxbase)[i] = (f32x4){0.f, 0.f, 0.f, 0.f};
    return;
  }
  const float* src;
  u16* dst;
  int i;
  if (gb < 8192) {
    src = X; dst = x16; i = gb * 256 + threadIdx.x;
  } else {
    src = W; dst = w16; i = (gb - 8192) * 256 + threadIdx.x;
  }
  const f32x4 a = ((const f32x4*)src)[2 * i];
  const f32x4 b = ((const f32x4*)src)[2 * i + 1];
  ushort4 lo, hi;
  lo.x = f2bf(a.x); lo.y = f2bf(a.y); lo.z = f2bf(a.z); lo.w = f2bf(a.w);
  hi.x = f2bf(b.x); hi.y = f2bf(b.y); hi.z = f2bf(b.z); hi.w = f2bf(b.w);
  ((ushort4*)dst)[2 * i] = lo;
  ((ushort4*)dst)[2 * i + 1] = hi;
}

// ---------------------------------------------------------------------------
// Kernel 1 v4: qkv = x @ w^T  (M=16384, K=1024, O=3072), bf16 in.
// 256x256 tile, BK=64, 512 thr = 8 waves (2M x 4N), mfma_f32_16x16x32_bf16.
// [identical resubmit of round-2 source: round-2 bench was an infra failure
//  ("container failed twice", no diagnostics); hazard/bounds audit found no
//  kernel defect -- resubmitting unchanged to disambiguate.]
//  (a) ONE barrier per phase (end only).  WAR: stage at phase p writes a unit
//      whose last ds_read drained (lgkmcnt(0)) before an earlier end-barrier;
//      RAW: tile-boundary vmcnt(4)+barrier retires exactly the units the next
//      tile reads (12-outstanding ledger verified).
//  (b) B-low fragments held in regs p0->p3: 28 -> 24 ds_read_b128 per tile.
//  (c) Epilogue: KV stored FRAGMENT-NATIVE (tile-linear, ushort4 coalesced,
//      decoded by ctx_colsum); Q bounced via the now-dead 128 KiB LDS in two
//      128-row passes -> dwordx4 stores, 256B segments (was 4B @ 256B stride).
// Stage schedule unchanged: p0 AH(t+1), p1 BL(t+1), p2 AL(t+2), p3 BH(t+2);
// vmcnt(4) at boundary (never 0 mid-loop).
// ---------------------------------------------------------------------------
__global__ __launch_bounds__(512, 2) void qkv_gemm(const u16* __restrict__ X,
                                                   const u16* __restrict__ W,
                                                   float* __restrict__ QOUT,
                                                   u16* __restrict__ KV) {
  __shared__ __attribute__((aligned(16))) u16 lds[8 * 128 * 64];  // 128 KiB

  const int t = threadIdx.x;
  const int D = blockIdx.x;
  const int xcd = D & 7;
  const int s = D >> 3;
  const int otile = s % 12;
  const int mtile = (s / 12) * 8 + xcd;
  const int oblk = otile << 8;
  const int mblk = mtile << 8;

  const int wv = t >> 6;
  const int l = t & 63;
  const int wm = wv >> 2;
  const int wnx = wv & 3;
  const int l15 = l & 15;
  const int lq = l >> 4;
  const int sp = t & 7;

  char* ldsc = (char*)lds;

  auto stageA = [&](int tau, int h, int par) {
#pragma unroll
    for (int j = 0; j < 2; j++) {
      const int ur = (j << 6) | (t >> 3);
      const int R = ((ur >> 6) << 7) | (h << 6) | (ur & 63);
      const u16* g = X + (size_t)(mblk + R) * 1024 + (tau << 6) +
                     ((sp ^ (ur & 7)) << 3);
      gload_lds16(g, ldsc + (((par << 2) | h) << 14) + (((j << 9) | t) << 4));
    }
  };
  auto stageB = [&](int tau, int h, int par) {
#pragma unroll
    for (int j = 0; j < 2; j++) {
      const int ur = (j << 6) | (t >> 3);
      const int R = ((ur >> 5) << 6) | (h << 5) | (ur & 31);
      const u16* g = W + (size_t)(oblk + R) * 1024 + (tau << 6) +
                     ((sp ^ (ur & 7)) << 3);
      gload_lds16(g,
                  ldsc + (((par << 2) | 2 | h) << 14) + (((j << 9) | t) << 4));
    }
  };

  const int co0 = (((l >> 4) ^ (l & 7)) << 4);
  const int co1 = ((((l >> 4) | 4) ^ (l & 7)) << 4);
  const int aOff = ((wm << 6) | l15) << 7;
  const int bOff = ((wnx << 5) | l15) << 7;

  bf16x8 bA[2][4], bL[2][2], bH[2][2];
  auto loadA = [&](int h, int par) {
    const char* base = ldsc + (((par << 2) | h) << 14) + aOff;
#pragma unroll
    for (int fm = 0; fm < 4; fm++) {
      bA[0][fm] = *(const bf16x8*)(base + (fm << 11) + co0);
      bA[1][fm] = *(const bf16x8*)(base + (fm << 11) + co1);
    }
  };
  auto loadB2 = [&](int nh, int par, bf16x8(&bb)[2][2]) {
    const char* base = ldsc + (((par << 2) | 2 | nh) << 14) + bOff;
#pragma unroll
    for (int fn = 0; fn < 2; fn++) {
      bb[0][fn] = *(const bf16x8*)(base + (fn << 11) + co0);
      bb[1][fn] = *(const bf16x8*)(base + (fn << 11) + co1);
    }
  };

  f32x4 acc[8][4];
#pragma unroll
  for (int i = 0; i < 8; i++)
#pragma unroll
    for (int j = 0; j < 4; j++) acc[i][j] = (f32x4){0.f, 0.f, 0.f, 0.f};

  auto mfma16 = [&](int ah, int nh, bf16x8(&bb)[2][2]) {
#pragma unroll
    for (int fm = 0; fm < 4; fm++)
#pragma unroll
      for (int fn = 0; fn < 2; fn++)
#pragma unroll
        for (int ks = 0; ks < 2; ks++)
          acc[(ah << 2) | fm][(nh << 1) | fn] =
              __builtin_amdgcn_mfma_f32_16x16x32_bf16(
                  bA[ks][fm], bb[ks][fn], acc[(ah << 2) | fm][(nh << 1) | fn],
                  0, 0, 0);
  };

  // prologue: 6 units; vmcnt(4) leaves AL1,BH1 in flight
  stageA(0, 0, 0);
  stageA(0, 1, 0);
  stageB(0, 0, 0);
  stageB(0, 1, 0);
  stageA(1, 0, 1);
  stageB(1, 1, 1);
  asm volatile("s_waitcnt vmcnt(4)" ::: "memory");
  __builtin_amdgcn_s_barrier();

#pragma unroll 1
  for (int tau = 0; tau < 16; tau++) {
    const int par = tau & 1;
    // phase 0: Q(0,0) = (A-low, B-low)
    loadA(0, par);
    loadB2(0, par, bL);
    if (tau < 15) stageA(tau + 1, 1, par ^ 1);
    asm volatile("s_waitcnt lgkmcnt(0)" ::: "memory");
    __builtin_amdgcn_s_setprio(1);
    mfma16(0, 0, bL);
    __builtin_amdgcn_s_setprio(0);
    __builtin_amdgcn_s_barrier();
    // phase 1: Q(0,1) = (A-low, B-high)
    loadB2(1, par, bH);
    if (tau < 15) stageB(tau + 1, 0, par ^ 1);
    asm volatile("s_waitcnt lgkmcnt(0)" ::: "memory");
    __builtin_amdgcn_s_setprio(1);
    mfma16(0, 1, bH);
    __builtin_amdgcn_s_setprio(0);
    __builtin_amdgcn_s_barrier();
    // phase 2: Q(1,1) = (A-high, B-high; bH regs reused)
    loadA(1, par);
    if (tau < 14) stageA(tau + 2, 0, par);
    asm volatile("s_waitcnt lgkmcnt(0)" ::: "memory");
    __builtin_amdgcn_s_setprio(1);
    mfma16(1, 1, bH);
    __builtin_amdgcn_s_setprio(0);
    __builtin_amdgcn_s_barrier();
    // phase 3: Q(1,0) = (A-high, B-low; bL regs held since p0 -- no ds reads)
    if (tau < 14) stageB(tau + 2, 1, par);
    __builtin_amdgcn_s_setprio(1);
    mfma16(1, 0, bL);
    __builtin_amdgcn_s_setprio(0);
    if (tau < 14) {
      asm volatile("s_waitcnt vmcnt(4)" ::: "memory");
    } else if (tau == 14) {
      asm volatile("s_waitcnt vmcnt(0)" ::: "memory");
    }
    __builtin_amdgcn_s_barrier();
  }

  // --- epilogue ------------------------------------------------------------
  // C/D 16x16 layout: col=lane&15, row=(lane>>4)*4+reg  [m89-verified]
  const bool is_q = (oblk < 1024);
  if (is_q) {
    // bounce through LDS (dead after main loop), 2 passes of 128 rows.
    float* LF = (float*)lds;
#pragma unroll 1
    for (int hh = 0; hh < 2; hh++) {
      __syncthreads();
      if (wm == hh) {
#pragma unroll
        for (int fm = 0; fm < 8; fm++) {
#pragma unroll
          for (int fn = 0; fn < 4; fn++) {
            const int colq = ((wnx << 2) | fn);  // col>>4
#pragma unroll
            for (int r = 0; r < 4; r++) {
              const int row = (fm << 4) + (lq << 2) + r;  // local 0..127
              const int g = colq ^ lq;                    // (row>>2)&3 == lq
              LF[(row << 8) + (g << 4) + l15] = acc[fm][fn][r];
            }
          }
        }
      }
      __syncthreads();
      const int nbase = mblk + (hh << 7);
#pragma unroll
      for (int p = 0; p < 16; p++) {
        const int u = (p << 9) + t;  // 0..8191 = 128 rows x 64 chunks
        const int row = u >> 6;
        const int c = u & 63;
        const int g = (c >> 2) ^ ((row >> 2) & 3);
        const f32x4 v4 = *(const f32x4*)&LF[(row << 8) + (g << 4) + ((c & 3) << 2)];
        const int rowg = nbase + row;
        const int bq = rowg >> 12, n = rowg & 4095;
        const int head = (oblk >> 6) + (c >> 4);
        *(f32x4*)&QOUT[((((size_t)((bq << 4) + head)) << 12) + n) * 64 +
                       ((c & 15) << 2)] = v4;
      }
    }
  } else {
    // fragment-native (tile-linear) KV: elem = tile*65536 + wv*8192
    //   + (fm*4+fn)*256 + lane*4 + r  -- ushort4 per (fm,fn), fully coalesced.
    u16* ks = KV + (((size_t)((mtile << 3) + (otile - 4))) << 16) + (wv << 13) +
              (l << 2);
#pragma unroll
    for (int fm = 0; fm < 8; fm++) {
#pragma unroll
      for (int fn = 0; fn < 4; fn++) {
        ushort4 sv;
        sv.x = f2bf(acc[fm][fn][0]);
        sv.y = f2bf(acc[fm][fn][1]);
        sv.z = f2bf(acc[fm][fn][2]);
        sv.w = f2bf(acc[fm][fn][3]);
        *(ushort4*)(ks + (((fm << 2) | fn) << 8)) = sv;
      }
    }
  }
}

// ---------------------------------------------------------------------------
// Kernel 2: ctxraw[bh][d][e] += sum_n exp(k[n,d]) * v[n,e]; colsum likewise.
// Load side rewritten for fragment-native KV: per 16-row chunk the (k or v)
// slab h*64..h*64+63 is 1024 CONTIGUOUS bf16 -> one dwordx2 per thread.
// ek/ev LDS layout & swizzle identical to before -> inner loop unchanged.
// ---------------------------------------------------------------------------
__global__ __launch_bounds__(256) void ctx_colsum(const u16* __restrict__ KV,
                                                  float* __restrict__ ctxraw,
                                                  float* __restrict__ colsum) {
  __shared__ __attribute__((aligned(16))) float ek[16 * 64];
  __shared__ __attribute__((aligned(16))) float ev[16 * 64];

  const int t = threadIdx.x;
  const int bh = blockIdx.y;
  const int b = bh >> 4, h = bh & 15;
  const int tr = t >> 4, tc = t & 15;

  // fragment decode: t = fn*64 + lane; elem = t*4 + r
  const int fnq = t >> 6;
  const int lane = t & 63;
  const int lq = lane >> 4;
  const int l15 = lane & 15;
  const int dd = (fnq << 4) | l15;  // d 0..63
  const int dq = dd >> 2, de = dd & 3;

  const int mtile = (b << 4) + blockIdx.x;  // 256 rows per block
  const size_t kb0 = (((size_t)((mtile << 3) + (h >> 2))) << 16) +
                     ((size_t)(h & 3) << 13) + ((size_t)t << 2);
  // chunk c adds ((c>>3)<<15) + ((c&7)<<10); v tile adds 4<<16.

  float acc[4][4] = {};
  float rs[4] = {0.f, 0.f, 0.f, 0.f};

  uint2 pk, pv;
  {
    pk = *(const uint2*)(KV + kb0);
    pv = *(const uint2*)(KV + kb0 + ((size_t)4 << 16));
  }

  for (int c = 0; c < 16; c++) {
    {
      const u16 kk[4] = {(u16)(pk.x & 0xffff), (u16)(pk.x >> 16),
                         (u16)(pk.y & 0xffff), (u16)(pk.y >> 16)};
      const u16 vb[4] = {(u16)(pv.x & 0xffff), (u16)(pv.x >> 16),
                         (u16)(pv.y & 0xffff), (u16)(pv.y >> 16)};
#pragma unroll
      for (int r = 0; r < 4; r++) {
        const int nl = (lq << 2) + r;
        const int idx = (nl << 6) | (((dq ^ nl) & 15) << 2) | de;
        ek[idx] = __expf(bf2f(kk[r]));
        ev[idx] = bf2f(vb[r]);
      }
    }
    __syncthreads();
    if (c + 1 < 16) {
      const int cn = c + 1;
      const size_t off = kb0 + ((size_t)(cn >> 3) << 15) + ((size_t)(cn & 7) << 10);
      pk = *(const uint2*)(KV + off);
      pv = *(const uint2*)(KV + off + ((size_t)4 << 16));
    }
#pragma unroll
    for (int nl = 0; nl < 16; nl++) {
      const f32x4 ka = *(const f32x4*)&ek[(nl << 6) + (((tr ^ nl) & 15) << 2)];
      const f32x4 vb = *(const f32x4*)&ev[(nl << 6) + (((tc ^ nl) & 15) << 2)];
      rs[0] += ka.x; rs[1] += ka.y; rs[2] += ka.z; rs[3] += ka.w;
#pragma unroll
      for (int a = 0; a < 4; a++) {
        acc[a][0] += ka[a] * vb.x;
        acc[a][1] += ka[a] * vb.y;
        acc[a][2] += ka[a] * vb.z;
        acc[a][3] += ka[a] * vb.w;
      }
    }
    __syncthreads();
  }

  float* dst = ctxraw + ((size_t)bh << 12);
#pragma unroll
  for (int a = 0; a < 4; a++)
#pragma unroll
    for (int e = 0; e < 4; e++)
      atomicAdd(&dst[((tr << 2) + a) * 64 + (tc << 2) + e], acc[a][e]);
  if (tc == 0) {
#pragma unroll
    for (int a = 0; a < 4; a++) atomicAdd(&colsum[(bh << 6) + (tr << 2) + a], rs[a]);
  }
}

// ---------------------------------------------------------------------------
// Kernel 3: out[bh,n,e] = (0.125/rowsum_n) * sum_d exp(q[n,d]) * ctx'[d,e]
// [unchanged]  Q staged as f32 in d_out [b,h,n,d], overwritten in-place.
// ---------------------------------------------------------------------------
__global__ __launch_bounds__(256) void out_kernel(const float* __restrict__ ctxraw,
                                                  const float* __restrict__ colsum,
                                                  float* __restrict__ OUT) {
  __shared__ __attribute__((aligned(16))) float ctxs[64 * 64];
  __shared__ __attribute__((aligned(16))) float qt[64 * 64];

  const int t = threadIdx.x;
  const int bh = blockIdx.y;
  const float* craw = ctxraw + ((size_t)bh << 12);
  const float* csum = colsum + (bh << 6);

#pragma unroll
  for (int j = 0; j < 16; j++) {
    const int idx = (j << 8) + t;
    ctxs[idx] = craw[idx] / csum[idx >> 6];
  }

  const int n0 = blockIdx.x << 6;
  float* qbase = OUT + (((size_t)bh << 12) + n0) * 64;
  {
#pragma unroll
    for (int p = 0; p < 4; p++) {
      const int c = (p << 8) + t;
      const int nl = c >> 4;
      const int dg = c & 15;
      const f32x4 qv = *(const f32x4*)(qbase + nl * 64 + (dg << 2));
      const int swz = ((nl >> 2) ^ dg) << 2;
#pragma unroll
      for (int e = 0; e < 4; e++) {
        const int d = (dg << 2) + e;
        qt[(d << 6) + swz + (nl & 3)] = __expf(qv[e]);
      }
    }
  }
  __syncthreads();

  const int tr = t >> 4, tc = t & 15;
  float acc[4][4] = {};
  f32x4 rsv = {0.f, 0.f, 0.f, 0.f};
#pragma unroll 4
  for (int d = 0; d < 64; d++) {
    const f32x4 qa = *(const f32x4*)&qt[(d << 6) + ((tr ^ (d >> 2)) << 2)];
    const f32x4 cb = *(const f32x4*)&ctxs[(d << 6) + (tc << 2)];
    rsv += qa;
#pragma unroll
    for (int a = 0; a < 4; a++) {
      acc[a][0] += qa[a] * cb.x;
      acc[a][1] += qa[a] * cb.y;
      acc[a][2] += qa[a] * cb.z;
      acc[a][3] += qa[a] * cb.w;
    }
  }
  __syncthreads();

#pragma unroll
  for (int a = 0; a < 4; a++) {
    const float inv = 0.125f / rsv[a];
    const int row = (tr << 2) + a;
    f32x4 pk;
    pk.x = acc[a][0] * inv;
    pk.y = acc[a][1] * inv;
    pk.z = acc[a][2] * inv;
    pk.w = acc[a][3] * inv;
    *(f32x4*)(qbase + row * 64 + (tc << 2)) = pk;
  }
}

extern "C" void kernel_launch(void* const* d_in, const int* in_sizes, int n_in,
                              void* d_out, int out_size, void* d_ws, size_t ws_size,
                              hipStream_t stream) {
  const float* Xf = (const float*)d_in[0];
  const float* Wf = (const float*)d_in[1];

  u16* x16 = (u16*)d_ws;
  u16* w16 = x16 + (size_t)16384 * 1024;
  u16* KV = w16 + (size_t)3072 * 1024;
  float* ctxraw = (float*)(KV + (size_t)16384 * 2048);
  float* colsum = ctxraw + 64 * 64 * 64;
  float* QOUT = (float*)d_out;

  cvt_all<<<dim3(9732), 256, 0, stream>>>(Xf, Wf, x16, w16, ctxraw);
  qkv_gemm<<<dim3(768), 512, 0, stream>>>(x16, w16, QOUT, KV);
  ctx_colsum<<<dim3(16, 64), 256, 0, stream>>>(KV, ctxraw, colsum);
  out_kernel<<<dim3(64, 64), 256, 0, stream>>>(ctxraw, colsum, QOUT);
}

// Round 5
// 264.681 us; speedup vs baseline: 1.3657x; 1.2274x over previous
//
#include <hip/hip_runtime.h>
#include <stdint.h>

typedef __attribute__((ext_vector_type(4))) float f32x4;
typedef __attribute__((ext_vector_type(8))) __bf16 bf16x8;
typedef unsigned short u16;

#define AS1 __attribute__((address_space(1)))
#define AS3 __attribute__((address_space(3)))

__device__ __forceinline__ u16 f2bf(float f) {
  uint32_t u = __float_as_uint(f);
  u += 0x7fffu + ((u >> 16) & 1u);
  return (u16)(u >> 16);
}
__device__ __forceinline__ float bf2f(u16 s) {
  return __uint_as_float(((uint32_t)s) << 16);
}

__device__ __forceinline__ void gload_lds16(const void* g, void* l) {
  __builtin_amdgcn_global_load_lds((const AS1 void*)g, (AS3 void*)l, 16, 0, 0);
}

__device__ __forceinline__ bf16x8 ones_bf16x8() {
  uint32_t o4[4] = {0x3F803F80u, 0x3F803F80u, 0x3F803F80u, 0x3F803F80u};
  return *(bf16x8*)o4;
}

// ---------------------------------------------------------------------------
// [ROUND-5 NOTE: bit-identical resubmit of the round-4 source.  Round-4 bench
//  died with "container failed twice" (no diagnostics) -- same signature as
//  round 2, which passed on identical resubmit in round 3.  Audit found no
//  deadlock path (all barriers unconditional, fixed trip counts), no OOB
//  (max KV index 33554431 < 33554432; LDS 32/40 KB), and the fragment-native
//  encode/decode + swizzle involutions verified symbolically.]
// ---------------------------------------------------------------------------

// ---------------------------------------------------------------------------
// Kernel 0: f32 -> bf16 convert (x, w) + zero-init of ctxraw/colsum. [unchanged]
// ---------------------------------------------------------------------------
__global__ __launch_bounds__(256) void cvt_all(const float* __restrict__ X,
                                               const float* __restrict__ W,
                                               u16* __restrict__ x16,
                                               u16* __restrict__ w16,
                                               float* __restrict__ ctxbase) {
  const int gb = blockIdx.x;
  if (gb >= 9728) {
    const int idx = (gb - 9728) * 256 + threadIdx.x;
    for (int i = idx; i < 66560; i += 1024)
      ((f32x4*)ctxbase)[i] = (f32x4){0.f, 0.f, 0.f, 0.f};
    return;
  }
  const float* src;
  u16* dst;
  int i;
  if (gb < 8192) {
    src = X; dst = x16; i = gb * 256 + threadIdx.x;
  } else {
    src = W; dst = w16; i = (gb - 8192) * 256 + threadIdx.x;
  }
  const f32x4 a = ((const f32x4*)src)[2 * i];
  const f32x4 b = ((const f32x4*)src)[2 * i + 1];
  ushort4 lo, hi;
  lo.x = f2bf(a.x); lo.y = f2bf(a.y); lo.z = f2bf(a.z); lo.w = f2bf(a.w);
  hi.x = f2bf(b.x); hi.y = f2bf(b.y); hi.z = f2bf(b.z); hi.w = f2bf(b.w);
  ((ushort4*)dst)[2 * i] = lo;
  ((ushort4*)dst)[2 * i + 1] = hi;
}

// ---------------------------------------------------------------------------
// Kernel 1 v4: qkv = x @ w^T  (M=16384, K=1024, O=3072), bf16 in.  [unchanged
// from round-3: 256x256 tile, 8-phase single-barrier schedule, counted vmcnt,
// fragment-native KV store, LDS-bounced Q store.]
// ---------------------------------------------------------------------------
__global__ __launch_bounds__(512, 2) void qkv_gemm(const u16* __restrict__ X,
                                                   const u16* __restrict__ W,
                                                   float* __restrict__ QOUT,
                                                   u16* __restrict__ KV) {
  __shared__ __attribute__((aligned(16))) u16 lds[8 * 128 * 64];  // 128 KiB

  const int t = threadIdx.x;
  const int D = blockIdx.x;
  const int xcd = D & 7;
  const int s = D >> 3;
  const int otile = s % 12;
  const int mtile = (s / 12) * 8 + xcd;
  const int oblk = otile << 8;
  const int mblk = mtile << 8;

  const int wv = t >> 6;
  const int l = t & 63;
  const int wm = wv >> 2;
  const int wnx = wv & 3;
  const int l15 = l & 15;
  const int lq = l >> 4;
  const int sp = t & 7;

  char* ldsc = (char*)lds;

  auto stageA = [&](int tau, int h, int par) {
#pragma unroll
    for (int j = 0; j < 2; j++) {
      const int ur = (j << 6) | (t >> 3);
      const int R = ((ur >> 6) << 7) | (h << 6) | (ur & 63);
      const u16* g = X + (size_t)(mblk + R) * 1024 + (tau << 6) +
                     ((sp ^ (ur & 7)) << 3);
      gload_lds16(g, ldsc + (((par << 2) | h) << 14) + (((j << 9) | t) << 4));
    }
  };
  auto stageB = [&](int tau, int h, int par) {
#pragma unroll
    for (int j = 0; j < 2; j++) {
      const int ur = (j << 6) | (t >> 3);
      const int R = ((ur >> 5) << 6) | (h << 5) | (ur & 31);
      const u16* g = W + (size_t)(oblk + R) * 1024 + (tau << 6) +
                     ((sp ^ (ur & 7)) << 3);
      gload_lds16(g,
                  ldsc + (((par << 2) | 2 | h) << 14) + (((j << 9) | t) << 4));
    }
  };

  const int co0 = (((l >> 4) ^ (l & 7)) << 4);
  const int co1 = ((((l >> 4) | 4) ^ (l & 7)) << 4);
  const int aOff = ((wm << 6) | l15) << 7;
  const int bOff = ((wnx << 5) | l15) << 7;

  bf16x8 bA[2][4], bL[2][2], bH[2][2];
  auto loadA = [&](int h, int par) {
    const char* base = ldsc + (((par << 2) | h) << 14) + aOff;
#pragma unroll
    for (int fm = 0; fm < 4; fm++) {
      bA[0][fm] = *(const bf16x8*)(base + (fm << 11) + co0);
      bA[1][fm] = *(const bf16x8*)(base + (fm << 11) + co1);
    }
  };
  auto loadB2 = [&](int nh, int par, bf16x8(&bb)[2][2]) {
    const char* base = ldsc + (((par << 2) | 2 | nh) << 14) + bOff;
#pragma unroll
    for (int fn = 0; fn < 2; fn++) {
      bb[0][fn] = *(const bf16x8*)(base + (fn << 11) + co0);
      bb[1][fn] = *(const bf16x8*)(base + (fn << 11) + co1);
    }
  };

  f32x4 acc[8][4];
#pragma unroll
  for (int i = 0; i < 8; i++)
#pragma unroll
    for (int j = 0; j < 4; j++) acc[i][j] = (f32x4){0.f, 0.f, 0.f, 0.f};

  auto mfma16 = [&](int ah, int nh, bf16x8(&bb)[2][2]) {
#pragma unroll
    for (int fm = 0; fm < 4; fm++)
#pragma unroll
      for (int fn = 0; fn < 2; fn++)
#pragma unroll
        for (int ks = 0; ks < 2; ks++)
          acc[(ah << 2) | fm][(nh << 1) | fn] =
              __builtin_amdgcn_mfma_f32_16x16x32_bf16(
                  bA[ks][fm], bb[ks][fn], acc[(ah << 2) | fm][(nh << 1) | fn],
                  0, 0, 0);
  };

  stageA(0, 0, 0);
  stageA(0, 1, 0);
  stageB(0, 0, 0);
  stageB(0, 1, 0);
  stageA(1, 0, 1);
  stageB(1, 1, 1);
  asm volatile("s_waitcnt vmcnt(4)" ::: "memory");
  __builtin_amdgcn_s_barrier();

#pragma unroll 1
  for (int tau = 0; tau < 16; tau++) {
    const int par = tau & 1;
    loadA(0, par);
    loadB2(0, par, bL);
    if (tau < 15) stageA(tau + 1, 1, par ^ 1);
    asm volatile("s_waitcnt lgkmcnt(0)" ::: "memory");
    __builtin_amdgcn_s_setprio(1);
    mfma16(0, 0, bL);
    __builtin_amdgcn_s_setprio(0);
    __builtin_amdgcn_s_barrier();
    loadB2(1, par, bH);
    if (tau < 15) stageB(tau + 1, 0, par ^ 1);
    asm volatile("s_waitcnt lgkmcnt(0)" ::: "memory");
    __builtin_amdgcn_s_setprio(1);
    mfma16(0, 1, bH);
    __builtin_amdgcn_s_setprio(0);
    __builtin_amdgcn_s_barrier();
    loadA(1, par);
    if (tau < 14) stageA(tau + 2, 0, par);
    asm volatile("s_waitcnt lgkmcnt(0)" ::: "memory");
    __builtin_amdgcn_s_setprio(1);
    mfma16(1, 1, bH);
    __builtin_amdgcn_s_setprio(0);
    __builtin_amdgcn_s_barrier();
    if (tau < 14) stageB(tau + 2, 1, par);
    __builtin_amdgcn_s_setprio(1);
    mfma16(1, 0, bL);
    __builtin_amdgcn_s_setprio(0);
    if (tau < 14) {
      asm volatile("s_waitcnt vmcnt(4)" ::: "memory");
    } else if (tau == 14) {
      asm volatile("s_waitcnt vmcnt(0)" ::: "memory");
    }
    __builtin_amdgcn_s_barrier();
  }

  const bool is_q = (oblk < 1024);
  if (is_q) {
    float* LF = (float*)lds;
#pragma unroll 1
    for (int hh = 0; hh < 2; hh++) {
      __syncthreads();
      if (wm == hh) {
#pragma unroll
        for (int fm = 0; fm < 8; fm++) {
#pragma unroll
          for (int fn = 0; fn < 4; fn++) {
            const int colq = ((wnx << 2) | fn);
#pragma unroll
            for (int r = 0; r < 4; r++) {
              const int row = (fm << 4) + (lq << 2) + r;
              const int g = colq ^ lq;
              LF[(row << 8) + (g << 4) + l15] = acc[fm][fn][r];
            }
          }
        }
      }
      __syncthreads();
      const int nbase = mblk + (hh << 7);
#pragma unroll
      for (int p = 0; p < 16; p++) {
        const int u = (p << 9) + t;
        const int row = u >> 6;
        const int c = u & 63;
        const int g = (c >> 2) ^ ((row >> 2) & 3);
        const f32x4 v4 = *(const f32x4*)&LF[(row << 8) + (g << 4) + ((c & 3) << 2)];
        const int rowg = nbase + row;
        const int bq = rowg >> 12, n = rowg & 4095;
        const int head = (oblk >> 6) + (c >> 4);
        *(f32x4*)&QOUT[((((size_t)((bq << 4) + head)) << 12) + n) * 64 +
                       ((c & 15) << 2)] = v4;
      }
    }
  } else {
    u16* ks = KV + (((size_t)((mtile << 3) + (otile - 4))) << 16) + (wv << 13) +
              (l << 2);
#pragma unroll
    for (int fm = 0; fm < 8; fm++) {
#pragma unroll
      for (int fn = 0; fn < 4; fn++) {
        ushort4 sv;
        sv.x = f2bf(acc[fm][fn][0]);
        sv.y = f2bf(acc[fm][fn][1]);
        sv.z = f2bf(acc[fm][fn][2]);
        sv.w = f2bf(acc[fm][fn][3]);
        *(ushort4*)(ks + (((fm << 2) | fn) << 8)) = sv;
      }
    }
  }
}

// ---------------------------------------------------------------------------
// Kernel 2 v2 (MFMA): ctxraw[bh][d][e] += sum_n exp(k[n,d]) * v[n,e];
// colsum[bh][d] += sum_n exp(k[n,d]) via an extra B=ones MFMA (wave 0).
// A = expk^T (d x n), B = v (n x e), both staged to LDS as [row][n] bf16
// transposed tiles via the fragment-native KV decode (each thread's uint2 =
// 4 consecutive n at fixed d -> one ds_write_b64).  XOR swizzle on 16B
// n-chunks: c ^= row&7, same involution on the read side.
// Grid (4 nsplits, 64 bh), 256 thr = 4 waves; wave w owns e-stripe w*16..+16.
// Per iter: 128 n staged (32KB HBM) -> 4 K-steps x 4 d-frags MFMA.
// Partials atomicAdd'd to ctxraw/colsum (zeroed by cvt_all).
// ---------------------------------------------------------------------------
__global__ __launch_bounds__(256) void ctx_colsum(const u16* __restrict__ KV,
                                                  float* __restrict__ ctxraw,
                                                  float* __restrict__ colsum) {
  __shared__ __attribute__((aligned(16))) u16 ekT[64 * 128];  // [d][n] swz
  __shared__ __attribute__((aligned(16))) u16 evT[64 * 128];  // [e][n] swz

  const int t = threadIdx.x;
  const int bh = blockIdx.y;
  const int b = bh >> 4, h = bh & 15;
  const int sgrp = blockIdx.x;  // 0..3 (n-split)
  const int w = t >> 6;
  const int l = t & 63;
  const int l15 = l & 15;
  const int lk = l >> 4;
  const int lq = (t >> 4) & 3;   // staging decode: t = fn<<6 | lq<<4 | l15
  const int d_st = (w << 4) | l15;  // fn == w for staging

  uint2 kr[8], vr[8];
  auto issue = [&](int it) {
    const int mt = (b << 4) + (sgrp << 2) + (it >> 1);
    const int wmb = it & 1;
    const size_t base = ((size_t)((mt << 3) + (h >> 2)) << 16) |
                        ((size_t)wmb << 15) | ((size_t)(h & 3) << 13) |
                        (size_t)(t << 2);
#pragma unroll
    for (int fm = 0; fm < 8; fm++) {
      kr[fm] = *(const uint2*)(KV + base + (fm << 10));
      vr[fm] = *(const uint2*)(KV + base + (fm << 10) + (4 << 16));
    }
  };
  auto stage = [&]() {
#pragma unroll
    for (int fm = 0; fm < 8; fm++) {
      const int c = (fm << 1) | (lq >> 1);
      const int off = (d_st << 8) + ((c ^ (d_st & 7)) << 4) + ((lq & 1) << 3);
      ushort4 es;
      es.x = f2bf(__expf(bf2f((u16)(kr[fm].x & 0xffff))));
      es.y = f2bf(__expf(bf2f((u16)(kr[fm].x >> 16))));
      es.z = f2bf(__expf(bf2f((u16)(kr[fm].y & 0xffff))));
      es.w = f2bf(__expf(bf2f((u16)(kr[fm].y >> 16))));
      *(ushort4*)((char*)ekT + off) = es;
      *(uint2*)((char*)evT + off) = vr[fm];
    }
  };

  f32x4 acc[4], acc1[4];
#pragma unroll
  for (int i = 0; i < 4; i++) {
    acc[i] = (f32x4){0.f, 0.f, 0.f, 0.f};
    acc1[i] = (f32x4){0.f, 0.f, 0.f, 0.f};
  }
  const bf16x8 ones = ones_bf16x8();
  const int eo = (w << 4) | l15;  // this wave's e for B-frags / C cols

  issue(0);
#pragma unroll 1
  for (int it = 0; it < 8; it++) {
    stage();
    if (it < 7) issue(it + 1);
    __syncthreads();
#pragma unroll
    for (int ksx = 0; ksx < 4; ksx++) {
      const bf16x8 bfrag = *(const bf16x8*)(
          (char*)evT + (eo << 8) + ((((ksx << 2) | lk) ^ (eo & 7)) << 4));
#pragma unroll
      for (int fmA = 0; fmA < 4; fmA++) {
        const int dA = (fmA << 4) | l15;
        const bf16x8 afrag = *(const bf16x8*)(
            (char*)ekT + (dA << 8) + ((((ksx << 2) | lk) ^ (dA & 7)) << 4));
        acc[fmA] = __builtin_amdgcn_mfma_f32_16x16x32_bf16(afrag, bfrag,
                                                           acc[fmA], 0, 0, 0);
        if (w == 0)
          acc1[fmA] = __builtin_amdgcn_mfma_f32_16x16x32_bf16(afrag, ones,
                                                              acc1[fmA], 0, 0, 0);
      }
    }
    __syncthreads();
  }

  float* dst = ctxraw + ((size_t)bh << 12);
#pragma unroll
  for (int fmA = 0; fmA < 4; fmA++)
#pragma unroll
    for (int r = 0; r < 4; r++) {
      const int d = (fmA << 4) + (lk << 2) + r;
      atomicAdd(&dst[(d << 6) + eo], acc[fmA][r]);
    }
  if (w == 0 && l15 == 0) {
#pragma unroll
    for (int fmA = 0; fmA < 4; fmA++)
#pragma unroll
      for (int r = 0; r < 4; r++) {
        const int d = (fmA << 4) + (lk << 2) + r;
        atomicAdd(&colsum[(bh << 6) + d], acc1[fmA][r]);
      }
  }
}

// ---------------------------------------------------------------------------
// Kernel 3 v2 (MFMA): out[bh,n,e] = (0.125/rowsum_n) * sum_d exp(q[n,d])*ctx'[d,e]
// ctx' = ctxraw/colsum normalized in-block (16KB L2-hot read), stored to LDS
// transposed [e][d] bf16 (B-operand layout).  expq staged [n][d] bf16 (A).
// rowsum via B=ones MFMA (consistent with the bf16 weights).  Q read from
// QOUT and overwritten in place (block owns its rows; stage-then-sync).
// Grid (16 ntiles, 64 bh), 256 thr = 4 waves; wave w owns rows w*64..+64.
// ---------------------------------------------------------------------------
__global__ __launch_bounds__(256) void out_kernel(const float* __restrict__ ctxraw,
                                                  const float* __restrict__ colsum,
                                                  float* __restrict__ OUT) {
  __shared__ __attribute__((aligned(16))) u16 qe[256 * 64];   // [n][d] swz 32KB
  __shared__ __attribute__((aligned(16))) u16 ctxT[64 * 64];  // [e][d] swz 8KB

  const int t = threadIdx.x;
  const int bh = blockIdx.y;
  const int n0 = blockIdx.x << 8;
  const float* craw = ctxraw + ((size_t)bh << 12);
  float* qbase = OUT + ((size_t)bh * 4096 + n0) * 64;

  // --- ctx' stage: normalize + transpose to [e][d] bf16 --------------------
#pragma unroll
  for (int p = 0; p < 4; p++) {
    const int vi = (p << 8) + t;  // f32x4 index 0..1023
    const int d = vi >> 4;
    const int e4 = (vi & 15) << 2;
    const f32x4 cv = *(const f32x4*)(craw + (vi << 2));
    const float inv = 1.0f / colsum[(bh << 6) + d];
#pragma unroll
    for (int j = 0; j < 4; j++) {
      const int e = e4 + j;
      *(u16*)((char*)ctxT + (e << 7) + (((d >> 3) ^ (e & 7)) << 4) +
              ((d & 7) << 1)) = f2bf(cv[j] * inv);
    }
  }
  // --- expq stage: [n][d] bf16, 8-elem chunks, c ^= row&7 ------------------
#pragma unroll
  for (int p = 0; p < 16; p++) {
    const int idx = (p << 8) + t;
    const int row = idx >> 4;
    const int c4 = idx & 15;
    const f32x4 qv = *(const f32x4*)(qbase + (row << 6) + (c4 << 2));
    ushort4 ev;
    ev.x = f2bf(__expf(qv.x));
    ev.y = f2bf(__expf(qv.y));
    ev.z = f2bf(__expf(qv.z));
    ev.w = f2bf(__expf(qv.w));
    *(ushort4*)((char*)qe + (row << 7) + (((c4 >> 1) ^ (row & 7)) << 4) +
                ((c4 & 1) << 3)) = ev;
  }
  __syncthreads();

  const int w = t >> 6;
  const int l = t & 63;
  const int l15 = l & 15;
  const int lk = l >> 4;

  f32x4 acc[4][4], acc1[4];
#pragma unroll
  for (int i = 0; i < 4; i++) {
    acc1[i] = (f32x4){0.f, 0.f, 0.f, 0.f};
#pragma unroll
    for (int j = 0; j < 4; j++) acc[i][j] = (f32x4){0.f, 0.f, 0.f, 0.f};
  }
  const bf16x8 ones = ones_bf16x8();

#pragma unroll
  for (int ksx = 0; ksx < 2; ksx++) {
    bf16x8 bfr[4];
#pragma unroll
    for (int fn = 0; fn < 4; fn++) {
      const int e = (fn << 4) | l15;
      bfr[fn] = *(const bf16x8*)((char*)ctxT + (e << 7) +
                                 ((((ksx << 2) | lk) ^ (e & 7)) << 4));
    }
#pragma unroll
    for (int fm = 0; fm < 4; fm++) {
      const int row = (w << 6) | (fm << 4) | l15;
      const bf16x8 afr = *(const bf16x8*)(
          (char*)qe + (row << 7) + ((((ksx << 2) | lk) ^ (row & 7)) << 4));
      acc1[fm] = __builtin_amdgcn_mfma_f32_16x16x32_bf16(afr, ones, acc1[fm],
                                                         0, 0, 0);
#pragma unroll
      for (int fn = 0; fn < 4; fn++)
        acc[fm][fn] = __builtin_amdgcn_mfma_f32_16x16x32_bf16(afr, bfr[fn],
                                                              acc[fm][fn], 0, 0, 0);
    }
  }

#pragma unroll
  for (int fm = 0; fm < 4; fm++) {
#pragma unroll
    for (int r = 0; r < 4; r++) {
      const int row = (w << 6) + (fm << 4) + (lk << 2) + r;
      const float inv = 0.125f / acc1[fm][r];
#pragma unroll
      for (int fn = 0; fn < 4; fn++)
        qbase[(row << 6) + (fn << 4) + l15] = acc[fm][fn][r] * inv;
    }
  }
}

extern "C" void kernel_launch(void* const* d_in, const int* in_sizes, int n_in,
                              void* d_out, int out_size, void* d_ws, size_t ws_size,
                              hipStream_t stream) {
  const float* Xf = (const float*)d_in[0];
  const float* Wf = (const float*)d_in[1];

  u16* x16 = (u16*)d_ws;
  u16* w16 = x16 + (size_t)16384 * 1024;
  u16* KV = w16 + (size_t)3072 * 1024;
  float* ctxraw = (float*)(KV + (size_t)16384 * 2048);
  float* colsum = ctxraw + 64 * 64 * 64;
  float* QOUT = (float*)d_out;

  cvt_all<<<dim3(9732), 256, 0, stream>>>(Xf, Wf, x16, w16, ctxraw);
  qkv_gemm<<<dim3(768), 512, 0, stream>>>(x16, w16, QOUT, KV);
  ctx_colsum<<<dim3(4, 64), 256, 0, stream>>>(KV, ctxraw, colsum);
  out_kernel<<<dim3(16, 64), 256, 0, stream>>>(ctxraw, colsum, QOUT);
}